// Round 4
// baseline (80.387 us; speedup 1.0000x reference)
//
#include <hip/hip_runtime.h>
#include <hip/hip_bf16.h>

typedef __bf16 bf16_t;
typedef __bf16 bf16x8 __attribute__((ext_vector_type(8)));
typedef float f32x4 __attribute__((ext_vector_type(4)));

#define NB 1024
#define ND 32
#define VD 64
#define NH 256
#define NK 2048

// workspace layout (bytes)
#define OFF_A    0                       // 1024*2048 bf16 = 4 MB
#define OFF_W1T  (4u*1024u*1024u)        // 32*256*2048 bf16 = 32 MB
#define OFF_W2T  (36u*1024u*1024u)       // 32*64*256 bf16 = 1 MB

#define GLD16(gsrc, ldst) \
  __builtin_amdgcn_global_load_lds((const __attribute__((address_space(1))) void*)(gsrc), \
                                   (__attribute__((address_space(3))) void*)(ldst), 16, 0, 0)

// ---------------- prep (unchanged from R3) ----------------
__global__ __launch_bounds__(256) void prep_kernel(
    const float* __restrict__ cv, const float* __restrict__ adj,
    const float* __restrict__ W1, const float* __restrict__ W2,
    bf16_t* __restrict__ A, bf16_t* __restrict__ W1T, bf16_t* __restrict__ W2T)
{
  __shared__ float Ls[64 * 67];
  int bx = blockIdx.x;
  int tid = threadIdx.x;
  if (bx < 4096) {
    int i = bx >> 7;
    int rem = bx & 127;
    int k0 = (rem >> 2) * 64;
    int h0 = (rem & 3) * 64;
    float a = adj[i * 32 + (k0 >> 6)];
    int rrow = tid >> 4, c4 = (tid & 15) * 4;
#pragma unroll
    for (int p = 0; p < 4; ++p) {
      int row = p * 16 + rrow;
      const float* src = W1 + ((size_t)(i * 2048 + k0 + row)) * 256 + h0 + c4;
      float4 v = *(const float4*)src;
#pragma unroll
      for (int j = 0; j < 4; ++j) Ls[row * 67 + c4 + j] = a * ((const float*)&v)[j];
    }
    __syncthreads();
#pragma unroll
    for (int p = 0; p < 2; ++p) {
      int u = p * 256 + tid;
      int h = u >> 3, c8 = u & 7;
      bf16x8 o;
#pragma unroll
      for (int j = 0; j < 8; ++j) o[j] = (bf16_t)Ls[(c8 * 8 + j) * 67 + h];
      *(bf16x8*)(W1T + ((size_t)(i * 256 + h0 + h)) * 2048 + k0 + c8 * 8) = o;
    }
  } else if (bx < 5120) {
    int t = (bx - 4096) * 256 + tid;
    const float4* s = (const float4*)cv + (size_t)t * 2;
    float4 v0 = s[0], v1 = s[1];
    bf16x8 o;
    o[0] = (bf16_t)v0.x; o[1] = (bf16_t)v0.y; o[2] = (bf16_t)v0.z; o[3] = (bf16_t)v0.w;
    o[4] = (bf16_t)v1.x; o[5] = (bf16_t)v1.y; o[6] = (bf16_t)v1.z; o[7] = (bf16_t)v1.w;
    *(bf16x8*)(A + (size_t)t * 8) = o;
  } else {
    int t = (bx - 5120) * 256 + tid;
    int i = t >> 11;
    int rem = t & 2047;
    int h8 = rem >> 6;
    int v = rem & 63;
    const float* src = W2 + ((size_t)(i * 256 + h8 * 8)) * 64 + v;
    bf16x8 o;
#pragma unroll
    for (int r = 0; r < 8; ++r) o[r] = (bf16_t)src[(size_t)r * 64];
    *(bf16x8*)(W2T + ((size_t)(i * 64 + v)) * 256 + h8 * 8) = o;
  }
}

// ---------------- fused main: 512 blocks x 256 thr, 64x256 tile, 3-deep pipeline, 2 blocks/CU ----
__global__ __launch_bounds__(256, 2) void sem_main_kernel(
    const bf16_t* __restrict__ A, const bf16_t* __restrict__ W1T,
    const bf16_t* __restrict__ W2T,
    const float* __restrict__ b1, const float* __restrict__ b2,
    const float* __restrict__ gamma, const float* __restrict__ beta,
    float* __restrict__ out)
{
  __shared__ char smem[61440];   // 3 x (A 4KB + B 16KB); epilogue Hs [64][264] bf16 = 33.8KB

  // XCD swizzle: 16 blocks of same group per XCD (B panel 1MB stays L2-hot)
  int p = blockIdx.x;
  int L = (p & 7) * 64 + (p >> 3);
  int i = L >> 4;          // group 0..31
  int brow = (L & 15) * 64;

  int tid = threadIdx.x;
  int lane = tid & 63;
  int wid = tid >> 6;      // 0..3 = column block
  int lhi = lane >> 4;
  int llo = lane & 15;

  const bf16_t* W1Ti = W1T + (size_t)i * 256 * 2048;

  // per-thread staging sources (pre-swizzled, G21); row of A tile = tid>>2, 16B chunk = tid&3
  int arow = tid >> 2, ac = tid & 3;
  const bf16_t* aSrc = A + (size_t)(brow + arow) * 2048 + (ac ^ ((arow >> 1) & 3)) * 8;
  const bf16_t* bSrc0 = W1Ti + (size_t)arow * 2048 + (ac ^ ((arow >> 1) & 3)) * 8;
  const bf16_t* bSrc1 = W1Ti + (size_t)(64 + arow) * 2048 + (ac ^ (((64 + arow) >> 1) & 3)) * 8;
  const bf16_t* bSrc2 = W1Ti + (size_t)(128 + arow) * 2048 + (ac ^ (((128 + arow) >> 1) & 3)) * 8;
  const bf16_t* bSrc3 = W1Ti + (size_t)(192 + arow) * 2048 + (ac ^ (((192 + arow) >> 1) & 3)) * 8;
  int ldsW = wid * 1024;   // wave-uniform LDS dest (lane*16 implicit)

  auto stage = [&](int b, int kt) {
    char* base = smem + b * 20480;
    GLD16(aSrc + kt * 32, base + ldsW);
    GLD16(bSrc0 + kt * 32, base + 4096 + ldsW);
    GLD16(bSrc1 + kt * 32, base + 8192 + ldsW);
    GLD16(bSrc2 + kt * 32, base + 12288 + ldsW);
    GLD16(bSrc3 + kt * 32, base + 16384 + ldsW);
  };

  // fragment LDS offsets (swizzled reads)
  int aOff[4], bOff[4];
#pragma unroll
  for (int m = 0; m < 4; ++m) {
    int row = m * 16 + llo;
    aOff[m] = row * 64 + ((lhi ^ ((row >> 1) & 3)) * 16);
  }
#pragma unroll
  for (int n = 0; n < 4; ++n) {
    int row = wid * 64 + n * 16 + llo;
    bOff[n] = 4096 + row * 64 + ((lhi ^ ((row >> 1) & 3)) * 16);
  }

  f32x4 acc[4][4];
#pragma unroll
  for (int m = 0; m < 4; ++m)
#pragma unroll
    for (int n = 0; n < 4; ++n) acc[m][n] = (f32x4){0.f, 0.f, 0.f, 0.f};

  auto compute = [&](int b) {
    const char* base = smem + b * 20480;
    bf16x8 af[4], bfr[4];
#pragma unroll
    for (int m = 0; m < 4; ++m) af[m] = *(const bf16x8*)(base + aOff[m]);
#pragma unroll
    for (int n = 0; n < 4; ++n) bfr[n] = *(const bf16x8*)(base + bOff[n]);
    __builtin_amdgcn_s_setprio(1);
#pragma unroll
    for (int m = 0; m < 4; ++m)
#pragma unroll
      for (int n = 0; n < 4; ++n)
        acc[m][n] = __builtin_amdgcn_mfma_f32_16x16x32_bf16(af[m], bfr[n], acc[m][n], 0, 0, 0);
    __builtin_amdgcn_s_setprio(0);
  };

  asm volatile("" ::: "memory");
  stage(0, 0); stage(1, 1);
  int bc = 0, bs = 2;
  for (int t = 0; t < 62; ++t) {
    asm volatile("s_waitcnt vmcnt(5) lgkmcnt(0)" ::: "memory");  // own tile-t loads landed
    __builtin_amdgcn_s_barrier();                                // all waves' tile-t landed
    asm volatile("" ::: "memory");
    stage(bs, t + 2);                    // overwrites buffer read at iter t-1 (barrier-safe)
    compute(bc);
    bc = (bc == 2) ? 0 : bc + 1;
    bs = (bs == 2) ? 0 : bs + 1;
  }
  asm volatile("s_waitcnt vmcnt(5) lgkmcnt(0)" ::: "memory");
  __builtin_amdgcn_s_barrier();
  asm volatile("" ::: "memory");
  compute(2);                            // tile 62
  asm volatile("s_waitcnt vmcnt(0) lgkmcnt(0)" ::: "memory");
  __builtin_amdgcn_s_barrier();
  asm volatile("" ::: "memory");
  compute(0);                            // tile 63
  __syncthreads();                       // drain before smem reuse

  // ---- epilogue 1: bias + exact gelu -> Hs [64][264] bf16 ----
  bf16_t* Hs = (bf16_t*)smem;
  float bias[4];
#pragma unroll
  for (int n = 0; n < 4; ++n) bias[n] = b1[i * 256 + wid * 64 + n * 16 + llo];
#pragma unroll
  for (int m = 0; m < 4; ++m) {
#pragma unroll
    for (int n = 0; n < 4; ++n) {
      int col = wid * 64 + n * 16 + llo;
#pragma unroll
      for (int r = 0; r < 4; ++r) {
        int row = m * 16 + lhi * 4 + r;     // D: row=(lane>>4)*4+reg, col=lane&15
        float x = acc[m][n][r] + bias[n];
        float gl = 0.5f * x * (1.0f + erff(x * 0.70710678118654752f));
        Hs[row * 264 + col] = (bf16_t)gl;
      }
    }
  }
  __syncthreads();

  // ---- GEMM2: Y(64x64) = Hs(64x256) @ W2T_i^T; W2T frags direct from global (L2-hot) ----
  f32x4 acc2[4];
#pragma unroll
  for (int n = 0; n < 4; ++n) acc2[n] = (f32x4){0.f, 0.f, 0.f, 0.f};
  const bf16_t* W2Ti = W2T + (size_t)i * 64 * 256;
#pragma unroll
  for (int kk = 0; kk < 8; ++kk) {
    int k = kk * 32 + lhi * 8;
    bf16x8 af = *(const bf16x8*)(Hs + (wid * 16 + llo) * 264 + k);
#pragma unroll
    for (int n = 0; n < 4; ++n) {
      bf16x8 bfr = *(const bf16x8*)(W2Ti + (size_t)(n * 16 + llo) * 256 + k);
      acc2[n] = __builtin_amdgcn_mfma_f32_16x16x32_bf16(af, bfr, acc2[n], 0, 0, 0);
    }
  }

  // ---- epilogue 2: bias + LayerNorm(v=64) + affine -> out ----
  float b2v[4], gam[4], bet[4];
#pragma unroll
  for (int n = 0; n < 4; ++n) {
    int v = n * 16 + llo;
    b2v[n] = b2[i * 64 + v];
    gam[n] = gamma[i * 64 + v];
    bet[n] = beta[i * 64 + v];
  }
#pragma unroll
  for (int r = 0; r < 4; ++r) {
    float yv[4], s = 0.f, sq = 0.f;
#pragma unroll
    for (int n = 0; n < 4; ++n) {
      yv[n] = acc2[n][r] + b2v[n];
      s += yv[n];
      sq += yv[n] * yv[n];
    }
#pragma unroll
    for (int off = 1; off < 16; off <<= 1) {
      s += __shfl_xor(s, off, 64);
      sq += __shfl_xor(sq, off, 64);
    }
    float mu = s * (1.0f / 64.0f);
    float var = sq * (1.0f / 64.0f) - mu * mu;
    float rstd = rsqrtf(var + 1e-5f);
    int row = brow + wid * 16 + lhi * 4 + r;
    float* op = out + ((size_t)row * 32 + i) * 64;
#pragma unroll
    for (int n = 0; n < 4; ++n)
      op[n * 16 + llo] = (yv[n] - mu) * rstd * gam[n] + bet[n];
  }
}

extern "C" void kernel_launch(void* const* d_in, const int* in_sizes, int n_in,
                              void* d_out, int out_size, void* d_ws, size_t ws_size,
                              hipStream_t stream) {
  const float* cv    = (const float*)d_in[0];
  const float* adj   = (const float*)d_in[1];
  const float* W1    = (const float*)d_in[2];
  const float* b1    = (const float*)d_in[3];
  const float* W2    = (const float*)d_in[4];
  const float* b2    = (const float*)d_in[5];
  const float* gamma = (const float*)d_in[6];
  const float* beta  = (const float*)d_in[7];
  float* out = (float*)d_out;

  bf16_t* Abf  = (bf16_t*)((char*)d_ws + OFF_A);
  bf16_t* W1T  = (bf16_t*)((char*)d_ws + OFF_W1T);
  bf16_t* W2T  = (bf16_t*)((char*)d_ws + OFF_W2T);

  prep_kernel<<<5376, 256, 0, stream>>>(cv, adj, W1, W2, Abf, W1T, W2T);
  sem_main_kernel<<<512, 256, 0, stream>>>(Abf, W1T, W2T, b1, b2, gamma, beta, out);
}

// Round 5
// 68.764 us; speedup vs baseline: 1.1690x; 1.1690x over previous
//
#include <hip/hip_runtime.h>
#include <hip/hip_bf16.h>

typedef __bf16 bf16_t;
typedef __bf16 bf16x8 __attribute__((ext_vector_type(8)));
typedef float f32x4 __attribute__((ext_vector_type(4)));

#define NB 1024
#define ND 32
#define VD 64
#define NH 256
#define NK 2048

// workspace layout (bytes)
#define OFF_A    0                       // 1024*2048 bf16 = 4 MB
#define OFF_W1T  (4u*1024u*1024u)        // 32*256*2048 bf16 = 32 MB
#define OFF_W2T  (36u*1024u*1024u)       // 32*64*256 bf16 = 1 MB

#define GLD16(gsrc, ldst) \
  __builtin_amdgcn_global_load_lds((const __attribute__((address_space(1))) void*)(gsrc), \
                                   (__attribute__((address_space(3))) void*)(ldst), 16, 0, 0)

// ---------------- prep (unchanged) ----------------
__global__ __launch_bounds__(256) void prep_kernel(
    const float* __restrict__ cv, const float* __restrict__ adj,
    const float* __restrict__ W1, const float* __restrict__ W2,
    bf16_t* __restrict__ A, bf16_t* __restrict__ W1T, bf16_t* __restrict__ W2T)
{
  __shared__ float Ls[64 * 67];
  int bx = blockIdx.x;
  int tid = threadIdx.x;
  if (bx < 4096) {
    int i = bx >> 7;
    int rem = bx & 127;
    int k0 = (rem >> 2) * 64;
    int h0 = (rem & 3) * 64;
    float a = adj[i * 32 + (k0 >> 6)];
    int rrow = tid >> 4, c4 = (tid & 15) * 4;
#pragma unroll
    for (int p = 0; p < 4; ++p) {
      int row = p * 16 + rrow;
      const float* src = W1 + ((size_t)(i * 2048 + k0 + row)) * 256 + h0 + c4;
      float4 v = *(const float4*)src;
#pragma unroll
      for (int j = 0; j < 4; ++j) Ls[row * 67 + c4 + j] = a * ((const float*)&v)[j];
    }
    __syncthreads();
#pragma unroll
    for (int p = 0; p < 2; ++p) {
      int u = p * 256 + tid;
      int h = u >> 3, c8 = u & 7;
      bf16x8 o;
#pragma unroll
      for (int j = 0; j < 8; ++j) o[j] = (bf16_t)Ls[(c8 * 8 + j) * 67 + h];
      *(bf16x8*)(W1T + ((size_t)(i * 256 + h0 + h)) * 2048 + k0 + c8 * 8) = o;
    }
  } else if (bx < 5120) {
    int t = (bx - 4096) * 256 + tid;
    const float4* s = (const float4*)cv + (size_t)t * 2;
    float4 v0 = s[0], v1 = s[1];
    bf16x8 o;
    o[0] = (bf16_t)v0.x; o[1] = (bf16_t)v0.y; o[2] = (bf16_t)v0.z; o[3] = (bf16_t)v0.w;
    o[4] = (bf16_t)v1.x; o[5] = (bf16_t)v1.y; o[6] = (bf16_t)v1.z; o[7] = (bf16_t)v1.w;
    *(bf16x8*)(A + (size_t)t * 8) = o;
  } else {
    int t = (bx - 5120) * 256 + tid;
    int i = t >> 11;
    int rem = t & 2047;
    int h8 = rem >> 6;
    int v = rem & 63;
    const float* src = W2 + ((size_t)(i * 256 + h8 * 8)) * 64 + v;
    bf16x8 o;
#pragma unroll
    for (int r = 0; r < 8; ++r) o[r] = (bf16_t)src[(size_t)r * 64];
    *(bf16x8*)(W2T + ((size_t)(i * 64 + v)) * 256 + h8 * 8) = o;
  }
}

// stage one half-tile (BK=32): A 8KB (1 load/thr) + B 16KB (2 loads/thr) into buffer BUF
#define STAGE3(BUF, HT) do { \
    char* _bb = smem + (BUF) * 24576; \
    GLD16(aSrc  + (size_t)(HT) * 32, _bb + ldsA); \
    GLD16(bSrc0 + (size_t)(HT) * 32, _bb + 8192  + ldsA); \
    GLD16(bSrc1 + (size_t)(HT) * 32, _bb + 16384 + ldsA); \
  } while (0)

#define MFMA_COL(N, BFR) \
  acc[0][N] = __builtin_amdgcn_mfma_f32_16x16x32_bf16(_af0, BFR, acc[0][N], 0, 0, 0); \
  acc[1][N] = __builtin_amdgcn_mfma_f32_16x16x32_bf16(_af1, BFR, acc[1][N], 0, 0, 0); \
  acc[2][N] = __builtin_amdgcn_mfma_f32_16x16x32_bf16(_af2, BFR, acc[2][N], 0, 0, 0); \
  acc[3][N] = __builtin_amdgcn_mfma_f32_16x16x32_bf16(_af3, BFR, acc[3][N], 0, 0, 0);

// one half-tile = 2 phases; DO_STAGE: issue half-tile HT+2; VMASM: waitcnt before closing barrier
#define PHASE_PAIR(BUF, HT, DO_STAGE, VMASM) do { \
    const char* _cb = smem + (BUF) * 24576; \
    bf16x8 _af0 = *(const bf16x8*)(_cb + aOff0); \
    bf16x8 _af1 = *(const bf16x8*)(_cb + aOff1); \
    bf16x8 _af2 = *(const bf16x8*)(_cb + aOff2); \
    bf16x8 _af3 = *(const bf16x8*)(_cb + aOff3); \
    bf16x8 _bf0 = *(const bf16x8*)(_cb + bOff0); \
    bf16x8 _bf1 = *(const bf16x8*)(_cb + bOff1); \
    if (DO_STAGE) { STAGE3((BUF + 2) & 3, (HT) + 2); } \
    asm volatile("" ::: "memory"); \
    __builtin_amdgcn_s_barrier(); \
    asm volatile("s_waitcnt lgkmcnt(0)" ::: "memory"); \
    __builtin_amdgcn_sched_barrier(0); \
    __builtin_amdgcn_s_setprio(1); \
    MFMA_COL(0, _bf0) \
    MFMA_COL(1, _bf1) \
    __builtin_amdgcn_s_setprio(0); \
    __builtin_amdgcn_sched_barrier(0); \
    asm volatile("" ::: "memory"); \
    __builtin_amdgcn_s_barrier(); \
    bf16x8 _bf2 = *(const bf16x8*)(_cb + bOff2); \
    bf16x8 _bf3 = *(const bf16x8*)(_cb + bOff3); \
    asm volatile("" ::: "memory"); \
    asm volatile(VMASM ::: "memory"); \
    __builtin_amdgcn_s_barrier(); \
    asm volatile("s_waitcnt lgkmcnt(0)" ::: "memory"); \
    __builtin_amdgcn_sched_barrier(0); \
    __builtin_amdgcn_s_setprio(1); \
    MFMA_COL(2, _bf2) \
    MFMA_COL(3, _bf3) \
    __builtin_amdgcn_s_setprio(0); \
    __builtin_amdgcn_sched_barrier(0); \
    asm volatile("" ::: "memory"); \
    __builtin_amdgcn_s_barrier(); \
  } while (0)

// ---------------- fused main: 256 blocks x 512 thr, 128x256 tile, 8-phase / 2 K-tiles ----------
__global__ __launch_bounds__(512, 2) void sem_main_kernel(
    const bf16_t* __restrict__ A, const bf16_t* __restrict__ W1T,
    const bf16_t* __restrict__ W2T,
    const float* __restrict__ b1, const float* __restrict__ b2,
    const float* __restrict__ gamma, const float* __restrict__ beta,
    float* __restrict__ out)
{
  __shared__ char smem[98304];   // 4 half-tile buffers x 24KB; epilogue Hs [128][264] bf16

  int p = blockIdx.x;
  int L = (p & 7) * 32 + (p >> 3);   // XCD swizzle: 8 same-group blocks per XCD
  int i = L >> 3;
  int brow = (L & 7) * 128;

  int tid = threadIdx.x;
  int lane = tid & 63;
  int wid = tid >> 6;     // 0..7
  int wr = wid >> 2;      // 0..1
  int wc = wid & 3;       // 0..3
  int lhi = lane >> 4;
  int llo = lane & 15;

  const bf16_t* W1Ti = W1T + (size_t)i * 256 * 2048;

  // staging sources (pre-swizzled, G21): row = tid>>2 (0..127), chunk = tid&3
  int arow = tid >> 2, ac = tid & 3;
  int sc0 = ac ^ ((arow >> 1) & 3);
  const bf16_t* aSrc  = A + (size_t)(brow + arow) * 2048 + sc0 * 8;
  const bf16_t* bSrc0 = W1Ti + (size_t)arow * 2048 + sc0 * 8;
  const bf16_t* bSrc1 = W1Ti + (size_t)(128 + arow) * 2048 + sc0 * 8;   // (128+r)>>1 &3 == r>>1 &3
  int ldsA = wid * 1024;   // wave-uniform LDS dest

  // fragment read offsets (swizzled): A rows wr*64+m*16+llo; B rows wc*64+n*16+llo
  int ar0 = wr * 64 + 0 * 16 + llo, ar1 = wr * 64 + 16 + llo, ar2 = wr * 64 + 32 + llo, ar3 = wr * 64 + 48 + llo;
  int aOff0 = ar0 * 64 + ((lhi ^ ((ar0 >> 1) & 3)) * 16);
  int aOff1 = ar1 * 64 + ((lhi ^ ((ar1 >> 1) & 3)) * 16);
  int aOff2 = ar2 * 64 + ((lhi ^ ((ar2 >> 1) & 3)) * 16);
  int aOff3 = ar3 * 64 + ((lhi ^ ((ar3 >> 1) & 3)) * 16);
  int br0 = wc * 64 + 0 * 16 + llo, br1 = wc * 64 + 16 + llo, br2 = wc * 64 + 32 + llo, br3 = wc * 64 + 48 + llo;
  int bOff0 = 8192 + br0 * 64 + ((lhi ^ ((br0 >> 1) & 3)) * 16);
  int bOff1 = 8192 + br1 * 64 + ((lhi ^ ((br1 >> 1) & 3)) * 16);
  int bOff2 = 8192 + br2 * 64 + ((lhi ^ ((br2 >> 1) & 3)) * 16);
  int bOff3 = 8192 + br3 * 64 + ((lhi ^ ((br3 >> 1) & 3)) * 16);

  f32x4 acc[4][4];
#pragma unroll
  for (int m = 0; m < 4; ++m)
#pragma unroll
    for (int n = 0; n < 4; ++n) acc[m][n] = (f32x4){0.f, 0.f, 0.f, 0.f};

  // prologue: stage half-tiles 0,1; wait for 0
  asm volatile("" ::: "memory");
  STAGE3(0, 0);
  STAGE3(1, 1);
  asm volatile("s_waitcnt vmcnt(3)" ::: "memory");
  __builtin_amdgcn_s_barrier();

  // 64 half-tiles (K=2048 / 32); steady-state vmcnt(3); drain at 62/63
  for (int htb = 0; htb < 60; htb += 4) {
    PHASE_PAIR(0, htb + 0, 1, "s_waitcnt vmcnt(3)");
    PHASE_PAIR(1, htb + 1, 1, "s_waitcnt vmcnt(3)");
    PHASE_PAIR(2, htb + 2, 1, "s_waitcnt vmcnt(3)");
    PHASE_PAIR(3, htb + 3, 1, "s_waitcnt vmcnt(3)");
  }
  PHASE_PAIR(0, 60, 1, "s_waitcnt vmcnt(3)");
  PHASE_PAIR(1, 61, 1, "s_waitcnt vmcnt(3)");
  PHASE_PAIR(2, 62, 0, "s_waitcnt vmcnt(0)");
  PHASE_PAIR(3, 63, 0, "");

  __syncthreads();   // drain before smem reuse

  // ---- epilogue 1: bias + exact gelu -> Hs [128][264] bf16 ----
  bf16_t* Hs = (bf16_t*)smem;
  float bias[4];
#pragma unroll
  for (int n = 0; n < 4; ++n) bias[n] = b1[i * 256 + wc * 64 + n * 16 + llo];
#pragma unroll
  for (int m = 0; m < 4; ++m) {
#pragma unroll
    for (int n = 0; n < 4; ++n) {
      int col = wc * 64 + n * 16 + llo;
#pragma unroll
      for (int r = 0; r < 4; ++r) {
        int row = wr * 64 + m * 16 + lhi * 4 + r;   // D: row=(lane>>4)*4+reg, col=lane&15
        float x = acc[m][n][r] + bias[n];
        float gl = 0.5f * x * (1.0f + erff(x * 0.70710678118654752f));
        Hs[row * 264 + col] = (bf16_t)gl;
      }
    }
  }
  __syncthreads();

  // ---- GEMM2: Y(128x64) = Hs(128x256) @ W2T_i^T; W2T from L2 ----
  f32x4 acc2[4];
#pragma unroll
  for (int n = 0; n < 4; ++n) acc2[n] = (f32x4){0.f, 0.f, 0.f, 0.f};
  const bf16_t* W2Ti = W2T + (size_t)i * 64 * 256;
#pragma unroll
  for (int kk = 0; kk < 8; ++kk) {
    int k = kk * 32 + lhi * 8;
    bf16x8 af = *(const bf16x8*)(Hs + (wid * 16 + llo) * 264 + k);
#pragma unroll
    for (int n = 0; n < 4; ++n) {
      bf16x8 bfr = *(const bf16x8*)(W2Ti + (size_t)(n * 16 + llo) * 256 + k);
      acc2[n] = __builtin_amdgcn_mfma_f32_16x16x32_bf16(af, bfr, acc2[n], 0, 0, 0);
    }
  }

  // ---- epilogue 2: bias + LayerNorm(v=64) + affine -> out ----
  float b2v[4], gam[4], bet[4];
#pragma unroll
  for (int n = 0; n < 4; ++n) {
    int v = n * 16 + llo;
    b2v[n] = b2[i * 64 + v];
    gam[n] = gamma[i * 64 + v];
    bet[n] = beta[i * 64 + v];
  }
#pragma unroll
  for (int r = 0; r < 4; ++r) {
    float yv[4], s = 0.f, sq = 0.f;
#pragma unroll
    for (int n = 0; n < 4; ++n) {
      yv[n] = acc2[n][r] + b2v[n];
      s += yv[n];
      sq += yv[n] * yv[n];
    }
#pragma unroll
    for (int off = 1; off < 16; off <<= 1) {
      s += __shfl_xor(s, off, 64);
      sq += __shfl_xor(sq, off, 64);
    }
    float mu = s * (1.0f / 64.0f);
    float var = sq * (1.0f / 64.0f) - mu * mu;
    float rstd = rsqrtf(var + 1e-5f);
    int row = brow + wid * 16 + lhi * 4 + r;
    float* op = out + ((size_t)row * 32 + i) * 64;
#pragma unroll
    for (int n = 0; n < 4; ++n)
      op[n * 16 + llo] = (yv[n] - mu) * rstd * gam[n] + bet[n];
  }
}

extern "C" void kernel_launch(void* const* d_in, const int* in_sizes, int n_in,
                              void* d_out, int out_size, void* d_ws, size_t ws_size,
                              hipStream_t stream) {
  const float* cv    = (const float*)d_in[0];
  const float* adj   = (const float*)d_in[1];
  const float* W1    = (const float*)d_in[2];
  const float* b1    = (const float*)d_in[3];
  const float* W2    = (const float*)d_in[4];
  const float* b2    = (const float*)d_in[5];
  const float* gamma = (const float*)d_in[6];
  const float* beta  = (const float*)d_in[7];
  float* out = (float*)d_out;

  bf16_t* Abf  = (bf16_t*)((char*)d_ws + OFF_A);
  bf16_t* W1T  = (bf16_t*)((char*)d_ws + OFF_W1T);
  bf16_t* W2T  = (bf16_t*)((char*)d_ws + OFF_W2T);

  prep_kernel<<<5376, 256, 0, stream>>>(cv, adj, W1, W2, Abf, W1T, W2T);
  sem_main_kernel<<<256, 512, 0, stream>>>(Abf, W1T, W2T, b1, b2, gamma, beta, out);
}